// Round 4
// baseline (361.960 us; speedup 1.0000x reference)
//
#include <hip/hip_runtime.h>

// Problem constants (fixed by setup_inputs)
static constexpr int V  = 5;
static constexpr int B  = 2;
static constexpr int C  = 32;
static constexpr int H  = 256;
static constexpr int W  = 320;
static constexpr int CN = 4;
static constexpr int HW = H * W;
static constexpr int CG = 8;   // channels per group (per wave)
static constexpr int NG = 4;   // groups per block
static constexpr int XT = W / 64;        // 5 x-tiles
static constexpr int NBLK = XT * H * B;  // 2560 fused blocks

// ws layout: params only now (96 floats)
static constexpr size_t PARAMS_OFF = 0;

typedef float f32x2 __attribute__((ext_vector_type(2)));
typedef float f32x4 __attribute__((ext_vector_type(4)));

// Alignment-safe paired load (backend emits unaligned-capable dwordx2)
__device__ __forceinline__ f32x2 ld2(const float* p) {
    f32x2 v;
    __builtin_memcpy(&v, p, sizeof(f32x2));
    return v;
}

// ---------------------------------------------------------------------------
// Setup: per (b, src view i=1..4) compute proj = M_i @ inv(M_0) -> 12 floats
// ---------------------------------------------------------------------------
__global__ void setup_proj_kernel(const float* __restrict__ pm, float* __restrict__ params) {
    int b = threadIdx.x;
    if (b >= B) return;

    float M[V][16];
    for (int v = 0; v < V; ++v) {
        const float* E  = pm + ((size_t)(b * V + v) * 2 + 0) * 16;
        const float* Km = pm + ((size_t)(b * V + v) * 2 + 1) * 16;
        for (int r = 0; r < 3; ++r)
            for (int c = 0; c < 4; ++c) {
                float s = 0.f;
                for (int k = 0; k < 3; ++k) s += Km[r * 4 + k] * E[k * 4 + c];
                M[v][r * 4 + c] = s;
            }
        for (int c = 0; c < 4; ++c) M[v][12 + c] = E[12 + c];
    }

    float A[9], bb[3];
    for (int r = 0; r < 3; ++r) {
        for (int c = 0; c < 3; ++c) A[r * 3 + c] = M[0][r * 4 + c];
        bb[r] = M[0][r * 4 + 3];
    }
    float det = A[0] * (A[4] * A[8] - A[5] * A[7])
              - A[1] * (A[3] * A[8] - A[5] * A[6])
              + A[2] * (A[3] * A[7] - A[4] * A[6]);
    float id = 1.f / det;
    float Ai[9];
    Ai[0] = (A[4] * A[8] - A[5] * A[7]) * id;
    Ai[1] = (A[2] * A[7] - A[1] * A[8]) * id;
    Ai[2] = (A[1] * A[5] - A[2] * A[4]) * id;
    Ai[3] = (A[5] * A[6] - A[3] * A[8]) * id;
    Ai[4] = (A[0] * A[8] - A[2] * A[6]) * id;
    Ai[5] = (A[2] * A[3] - A[0] * A[5]) * id;
    Ai[6] = (A[3] * A[7] - A[4] * A[6]) * id;
    Ai[7] = (A[1] * A[6] - A[0] * A[7]) * id;
    Ai[8] = (A[0] * A[4] - A[1] * A[3]) * id;
    float bi[3];
    for (int r = 0; r < 3; ++r)
        bi[r] = -(Ai[r * 3 + 0] * bb[0] + Ai[r * 3 + 1] * bb[1] + Ai[r * 3 + 2] * bb[2]);

    float Minv[16];
    for (int r = 0; r < 3; ++r) {
        for (int c = 0; c < 3; ++c) Minv[r * 4 + c] = Ai[r * 3 + c];
        Minv[r * 4 + 3] = bi[r];
    }
    Minv[12] = 0.f; Minv[13] = 0.f; Minv[14] = 0.f; Minv[15] = 1.f;

    for (int v = 1; v < V; ++v) {
        float* dst = params + (size_t)(b * (V - 1) + (v - 1)) * 12;
        for (int r = 0; r < 3; ++r)
            for (int c = 0; c < 4; ++c) {
                float s = 0.f;
                for (int k = 0; k < 4; ++k) s += M[v][r * 4 + k] * Minv[k * 4 + c];
                dst[r * 4 + c] = s;
            }
    }
}

// ---------------------------------------------------------------------------
// Fused kernel: one block per (b, y, x-tile). Block = 64 px x 4 ch-groups.
// Each thread accumulates volsum[k] over ALL 4 source views, LDS-reduces
// across channel groups, normalizes by locally-computed wsum, then the block
// broadcast-writes the 128 output planes with regular cached stores.
//
// v4 (fixing v3's codegen failure): the wave-uniform row-1 skip is kept, but
// now the FAST path (row-0 only) is the only batched/unrolled body; the
// generic 4-corner fallback is a compact scalar (c,k) loop with minimal live
// registers, and ib1/cy1 are computed only inside it. v3's dual fully-batched
// paths drove VGPR 56->112 and occupancy 38%->21%, which outweighed the VMEM
// savings. Target here: VGPR ~56, occupancy ~38%, half the VMEM instructions.
// ---------------------------------------------------------------------------
__global__ __launch_bounds__(256) void fused_kernel(
    const float* __restrict__ depth_values,   // (B,1,H,W)
    const float* __restrict__ features,       // (V,B,C,H,W)
    const float* __restrict__ depth_interval, // (B,1,H,W)
    const float* __restrict__ view_weights,   // (B,V-1,H,W)
    const float* __restrict__ params,         // (B,V-1,12)
    float* __restrict__ out)                  // (B,C*CN,H,W)
{
    const int tid = threadIdx.x;
    const int p   = tid & 63;
    const int g   = tid >> 6;

    // bijective XCD swizzle: NBLK % 8 == 0, chunk = 320
    const int d  = blockIdx.x;
    const int l  = (d & 7) * (NBLK / 8) + (d >> 3);
    const int xt = l % XT;
    const int r2 = l / XT;          // 0..511
    const int y  = r2 & (H - 1);
    const int b  = r2 >> 8;

    const int x   = xt * 64 + p;
    const int pix = y * W + x;

    __shared__ float sp4[48];                // 4 views x 12 params
    __shared__ float sred[NG][CN][64];       // cross-group reduce
    __shared__ float sim_lds[CN][64];        // normalized sim for store phase
    if (tid < 48) sp4[tid] = params[(size_t)b * 48 + tid];
    __syncthreads();

    const float invd = 1.f / depth_values[(size_t)b * HW + pix];
    const float itv  = depth_interval[(size_t)b * HW + pix];
    const float low  = invd - (CN * 0.5f) * itv;
    const float step = (CN * itv) / (float)(CN - 1);
    float dep[CN];
#pragma unroll
    for (int k = 0; k < CN; ++k) dep[k] = 1.f / (low + (float)k * step);

    // this group's reference channels: read exactly once globally -> NT load
    const float* refp = features + ((size_t)b * C + g * CG) * HW + pix;
    float rf[CG];
#pragma unroll
    for (int c = 0; c < CG; ++c) rf[c] = __builtin_nontemporal_load(refp + (size_t)c * HW);

    const float fx = (float)x, fy = (float)y;

    float volsum[CN] = {0.f, 0.f, 0.f, 0.f};
    float wsum = 1e-5f;

    for (int iv = 0; iv < V - 1; ++iv) {
        const float* spv = &sp4[iv * 12];
        const float rx = spv[0] * fx + spv[1] * fy + spv[2];
        const float ry = spv[4] * fx + spv[5] * fy + spv[6];
        const float rz = spv[8] * fx + spv[9] * fy + spv[10];
        const float tx = spv[3], ty = spv[7], tz = spv[11];

        const float vw = view_weights[((size_t)b * (V - 1) + iv) * HW + pix];
        wsum += vw;
        const float scale = vw * (1.f / (float)C);

        const float* src = features + ((size_t)((iv + 1) * B + b) * C + g * CG) * HW;

        int   ib0[CN], y0s[CN];
        float wA0[CN], wB0[CN], wA1[CN], wB1[CN];
#pragma unroll
        for (int k = 0; k < CN; ++k) {
            const float dd = dep[k];
            const float px = rx * dd + tx;
            const float py = ry * dd + ty;
            const float pz = rz * dd + tz;
            const float iz = 1.f / pz;
            const float gx = px * iz;
            const float gy = py * iz;

            const float x0f = floorf(gx), y0f = floorf(gy);
            const float wx1 = gx - x0f, wy1 = gy - y0f;
            const float wx0 = 1.f - wx1, wy0 = 1.f - wy1;
            const int x0 = (int)x0f, y0 = (int)y0f;
            const int x1 = x0 + 1, y1 = y0 + 1;

            const bool vx0 = (x0 >= 0) && (x0 <= W - 1);
            const bool vx1 = (x1 >= 0) && (x1 <= W - 1);
            const bool vy0 = (y0 >= 0) && (y0 <= H - 1);
            const bool vy1 = (y1 >= 0) && (y1 <= H - 1);

            const int cy0 = min(max(y0, 0), H - 1);
            const int bx  = min(max(x0, 0), W - 2);
            const int s   = x0 - bx;   // {-1, 0, 1} (else all weights 0)

            const float w00 = wx0 * wy0 * ((vx0 && vy0) ? scale : 0.f);
            const float w10 = wx1 * wy0 * ((vx1 && vy0) ? scale : 0.f);
            const float w01 = wx0 * wy1 * ((vx0 && vy1) ? scale : 0.f);
            const float w11 = wx1 * wy1 * ((vx1 && vy1) ? scale : 0.f);

            wA0[k] = (s == 0) ? w00 : ((s == -1) ? w10 : 0.f);
            wB0[k] = (s == 0) ? w10 : ((s == 1) ? w00 : 0.f);
            wA1[k] = (s == 0) ? w01 : ((s == -1) ? w11 : 0.f);
            wB1[k] = (s == 0) ? w11 : ((s == 1) ? w01 : 0.f);

            ib0[k] = cy0 * W + bx;
            y0s[k] = y0;
        }

        // does any lane need the second bilinear row this view?
        bool need1 = false;
#pragma unroll
        for (int k = 0; k < CN; ++k)
            need1 = need1 || (wA1[k] != 0.f) || (wB1[k] != 0.f);

        if (!__any(need1)) {
            // FAST path (hot): row-0 only, batched 4ch x 4depth loads.
#pragma unroll
            for (int cc = 0; cc < CG; cc += 4) {
                f32x2 P[4][CN];
#pragma unroll
                for (int c = 0; c < 4; ++c) {
                    const float* fc = src + (size_t)(cc + c) * HW;
#pragma unroll
                    for (int k = 0; k < CN; ++k)
                        P[c][k] = ld2(fc + ib0[k]);
                }
#pragma unroll
                for (int c = 0; c < 4; ++c) {
                    const float rfc = rf[cc + c];
#pragma unroll
                    for (int k = 0; k < CN; ++k) {
                        float t = wA0[k] * P[c][k].x;
                        t = fmaf(wB0[k], P[c][k].y, t);
                        volsum[k] = fmaf(rfc, t, volsum[k]);
                    }
                }
            }
        } else {
            // GENERIC fallback (cold): compact scalar loops, minimal registers.
            int ib1[CN];
#pragma unroll
            for (int k = 0; k < CN; ++k) {
                const int y0 = y0s[k];
                const int dlt = (y0 >= 0 && y0 <= H - 2) ? W : 0;
                ib1[k] = ib0[k] + dlt;
            }
#pragma unroll 1
            for (int c = 0; c < CG; ++c) {
                const float* fc  = src + (size_t)c * HW;
                const float  rfc = rf[c];
#pragma unroll 1
                for (int k = 0; k < CN; ++k) {
                    const f32x2 a = ld2(fc + ib0[k]);
                    const f32x2 bb2 = ld2(fc + ib1[k]);
                    float t = wA0[k] * a.x;
                    t = fmaf(wB0[k], a.y, t);
                    t = fmaf(wA1[k], bb2.x, t);
                    t = fmaf(wB1[k], bb2.y, t);
                    volsum[k] = fmaf(rfc, t, volsum[k]);
                }
            }
        }
    }

    // cross-group reduce + normalize (NG == CN: group g owns depth k = g)
#pragma unroll
    for (int k = 0; k < CN; ++k) sred[g][k][p] = volsum[k];
    __syncthreads();

    {
        const int k = g;
        const float s = sred[0][k][p] + sred[1][k][p] + sred[2][k][p] + sred[3][k][p];
        sim_lds[k][p] = s * (1.f / wsum);   // every thread has wsum for its px
    }
    __syncthreads();

    // broadcast-write 128 planes x 64 px (32 KB) with regular cached stores.
    // thread: quad = tid&15 (4-px f32x4), pc = tid>>4; 8 planes per thread.
    {
        const int quad = tid & 15;
        const int pc   = tid >> 4;
        float* op = out + (size_t)b * C * CN * HW + y * W + xt * 64 + quad * 4;
#pragma unroll
        for (int j = 0; j < 8; ++j) {
            const int plane = pc * 8 + j;          // 0..127, each exactly once
            const int k     = plane & 3;           // == j & 3
            const f32x4 v   = *(const f32x4*)&sim_lds[k][quad * 4];
            *(f32x4*)(op + (size_t)plane * HW) = v;
        }
    }
}

extern "C" void kernel_launch(void* const* d_in, const int* in_sizes, int n_in,
                              void* d_out, int out_size, void* d_ws, size_t ws_size,
                              hipStream_t stream) {
    const float* depth_values   = (const float*)d_in[0];
    const float* features       = (const float*)d_in[1];
    const float* proj_matrices  = (const float*)d_in[2];
    const float* depth_interval = (const float*)d_in[3];
    const float* view_weights   = (const float*)d_in[7];
    float* out    = (float*)d_out;
    float* params = (float*)d_ws + PARAMS_OFF;    // 96 floats

    setup_proj_kernel<<<1, B, 0, stream>>>(proj_matrices, params);

    fused_kernel<<<NBLK, 256, 0, stream>>>(depth_values, features, depth_interval,
                                           view_weights, params, out);
}

// Round 5
// 278.511 us; speedup vs baseline: 1.2996x; 1.2996x over previous
//
#include <hip/hip_runtime.h>

// Problem constants (fixed by setup_inputs)
static constexpr int V  = 5;
static constexpr int B  = 2;
static constexpr int C  = 32;
static constexpr int H  = 256;
static constexpr int W  = 320;
static constexpr int CN = 4;
static constexpr int HW = H * W;
static constexpr int CG = 8;   // channels per group (per wave)
static constexpr int NG = 4;   // groups per block
static constexpr int XT = W / 64;        // 5 x-tiles
static constexpr int NBLK = XT * H * B;  // 2560 fused blocks

// ws layout: params only (96 floats)
static constexpr size_t PARAMS_OFF = 0;

typedef float f32x2 __attribute__((ext_vector_type(2)));
typedef float f32x4 __attribute__((ext_vector_type(4)));

// Alignment-safe paired load (backend emits unaligned-capable dwordx2)
__device__ __forceinline__ f32x2 ld2(const float* p) {
    f32x2 v;
    __builtin_memcpy(&v, p, sizeof(f32x2));
    return v;
}

// ---------------------------------------------------------------------------
// Setup: per (b, src view i=1..4) compute proj = M_i @ inv(M_0) -> 12 floats
// ---------------------------------------------------------------------------
__global__ void setup_proj_kernel(const float* __restrict__ pm, float* __restrict__ params) {
    int b = threadIdx.x;
    if (b >= B) return;

    float M[V][16];
    for (int v = 0; v < V; ++v) {
        const float* E  = pm + ((size_t)(b * V + v) * 2 + 0) * 16;
        const float* Km = pm + ((size_t)(b * V + v) * 2 + 1) * 16;
        for (int r = 0; r < 3; ++r)
            for (int c = 0; c < 4; ++c) {
                float s = 0.f;
                for (int k = 0; k < 3; ++k) s += Km[r * 4 + k] * E[k * 4 + c];
                M[v][r * 4 + c] = s;
            }
        for (int c = 0; c < 4; ++c) M[v][12 + c] = E[12 + c];
    }

    float A[9], bb[3];
    for (int r = 0; r < 3; ++r) {
        for (int c = 0; c < 3; ++c) A[r * 3 + c] = M[0][r * 4 + c];
        bb[r] = M[0][r * 4 + 3];
    }
    float det = A[0] * (A[4] * A[8] - A[5] * A[7])
              - A[1] * (A[3] * A[8] - A[5] * A[6])
              + A[2] * (A[3] * A[7] - A[4] * A[6]);
    float id = 1.f / det;
    float Ai[9];
    Ai[0] = (A[4] * A[8] - A[5] * A[7]) * id;
    Ai[1] = (A[2] * A[7] - A[1] * A[8]) * id;
    Ai[2] = (A[1] * A[5] - A[2] * A[4]) * id;
    Ai[3] = (A[5] * A[6] - A[3] * A[8]) * id;
    Ai[4] = (A[0] * A[8] - A[2] * A[6]) * id;
    Ai[5] = (A[2] * A[3] - A[0] * A[5]) * id;
    Ai[6] = (A[3] * A[7] - A[4] * A[6]) * id;
    Ai[7] = (A[1] * A[6] - A[0] * A[7]) * id;
    Ai[8] = (A[0] * A[4] - A[1] * A[3]) * id;
    float bi[3];
    for (int r = 0; r < 3; ++r)
        bi[r] = -(Ai[r * 3 + 0] * bb[0] + Ai[r * 3 + 1] * bb[1] + Ai[r * 3 + 2] * bb[2]);

    float Minv[16];
    for (int r = 0; r < 3; ++r) {
        for (int c = 0; c < 3; ++c) Minv[r * 4 + c] = Ai[r * 3 + c];
        Minv[r * 4 + 3] = bi[r];
    }
    Minv[12] = 0.f; Minv[13] = 0.f; Minv[14] = 0.f; Minv[15] = 1.f;

    for (int v = 1; v < V; ++v) {
        float* dst = params + (size_t)(b * (V - 1) + (v - 1)) * 12;
        for (int r = 0; r < 3; ++r)
            for (int c = 0; c < 4; ++c) {
                float s = 0.f;
                for (int k = 0; k < 4; ++k) s += M[v][r * 4 + k] * Minv[k * 4 + c];
                dst[r * 4 + c] = s;
            }
    }
}

// ---------------------------------------------------------------------------
// Fused kernel v5: LDS row-staged gather.
// Block = (b, y, x-tile): 64 px x 4 ch-groups, 2560 blocks.
// Insight: the per-lane gather addresses are scattered over a ~50*view-pixel
// span (per-pixel random depth), so each global ld2 touches many cache lines
// and the kernel is bound by VMEM address throughput (~34 cyc/instr). But the
// ROW range needed is only {y-1, y, y+1} (gy == y up to ulp; floor lands on
// y-1 or y). So: stage 3 full source rows x 2 channels per phase into LDS
// with coalesced f32x4 loads, gather from LDS (bank-uniform: 320 % 32 == 0).
// Wave-uniform row-range check -> identical verdict for all 4 waves (same
// pixels), so block barriers inside the branch are safe; generic data takes
// the cold compact global-gather fallback.
// sred/sim buffers alias the stage buffer (dead after last phase): LDS ~31 KB
// -> 5 blocks/CU. Row-sharing XCD swizzle: the 5 x-tiles of a row and
// adjacent rows land on the same XCD for L2 reuse of staged rows.
// ---------------------------------------------------------------------------
__global__ __launch_bounds__(256) void fused_kernel(
    const float* __restrict__ depth_values,   // (B,1,H,W)
    const float* __restrict__ features,       // (V,B,C,H,W)
    const float* __restrict__ depth_interval, // (B,1,H,W)
    const float* __restrict__ view_weights,   // (B,V-1,H,W)
    const float* __restrict__ params,         // (B,V-1,12)
    float* __restrict__ out)                  // (B,C*CN,H,W)
{
    const int tid = threadIdx.x;
    const int p   = tid & 63;
    const int g   = tid >> 6;

    // row-sharing XCD swizzle: class r8 = d&7 -> one XCD residue; within a
    // class, blocks sweep x-tiles fastest, then a contiguous 64-row slab.
    const int d   = blockIdx.x;
    const int u   = d >> 3;             // 0..319
    const int r8  = d & 7;              // XCD class
    const int xt  = u % XT;             // 0..4
    const int rid = r8 * 64 + u / XT;   // 0..511 (bijective)
    const int y   = rid & (H - 1);
    const int b   = rid >> 8;

    const int x   = xt * 64 + p;
    const int pix = y * W + x;

    __shared__ float sp4[48];            // 4 views x 12 params
    __shared__ float stage[NG][1920];    // 2 ch x 3 rows x 320 per group (30.7 KB)
    float* const sredp = &stage[0][0];   // aliased post-gather: [NG][CN][64]
    float* const simp  = &stage[0][1024];// aliased post-gather: [CN][64]

    if (tid < 48) sp4[tid] = params[(size_t)b * 48 + tid];
    __syncthreads();

    const float invd = 1.f / depth_values[(size_t)b * HW + pix];
    const float itv  = depth_interval[(size_t)b * HW + pix];
    const float low  = invd - (CN * 0.5f) * itv;
    const float step = (CN * itv) / (float)(CN - 1);
    float dep[CN];
#pragma unroll
    for (int k = 0; k < CN; ++k) dep[k] = 1.f / (low + (float)k * step);

    // this group's reference channels: read exactly once globally -> NT load
    const float* refp = features + ((size_t)b * C + g * CG) * HW + pix;
    float rf[CG];
#pragma unroll
    for (int c = 0; c < CG; ++c) rf[c] = __builtin_nontemporal_load(refp + (size_t)c * HW);

    const float fx = (float)x, fy = (float)y;

    float volsum[CN] = {0.f, 0.f, 0.f, 0.f};
    float wsum = 1e-5f;

    for (int iv = 0; iv < V - 1; ++iv) {
        const float* spv = &sp4[iv * 12];
        const float rx = spv[0] * fx + spv[1] * fy + spv[2];
        const float ry = spv[4] * fx + spv[5] * fy + spv[6];
        const float rz = spv[8] * fx + spv[9] * fy + spv[10];
        const float tx = spv[3], ty = spv[7], tz = spv[11];

        const float vw = view_weights[((size_t)b * (V - 1) + iv) * HW + pix];
        wsum += vw;
        const float scale = vw * (1.f / (float)C);

        const float* srcg = features + ((size_t)((iv + 1) * B + b) * C + g * CG) * HW;

        int   bx_[CN], y0_[CN];
        float wA0[CN], wB0[CN], wA1[CN], wB1[CN];
#pragma unroll
        for (int k = 0; k < CN; ++k) {
            const float dd = dep[k];
            const float px = rx * dd + tx;
            const float py = ry * dd + ty;
            const float pz = rz * dd + tz;
            const float iz = 1.f / pz;
            const float gx = px * iz;
            const float gy = py * iz;

            const float x0f = floorf(gx), y0f = floorf(gy);
            const float wx1 = gx - x0f, wy1 = gy - y0f;
            const float wx0 = 1.f - wx1, wy0 = 1.f - wy1;
            const int x0 = (int)x0f, y0 = (int)y0f;
            const int x1 = x0 + 1, y1 = y0 + 1;

            const bool vx0 = (x0 >= 0) && (x0 <= W - 1);
            const bool vx1 = (x1 >= 0) && (x1 <= W - 1);
            const bool vy0 = (y0 >= 0) && (y0 <= H - 1);
            const bool vy1 = (y1 >= 0) && (y1 <= H - 1);

            const int bx = min(max(x0, 0), W - 2);
            const int s  = x0 - bx;   // {-1, 0, 1} (else all weights 0)

            const float w00 = wx0 * wy0 * ((vx0 && vy0) ? scale : 0.f);
            const float w10 = wx1 * wy0 * ((vx1 && vy0) ? scale : 0.f);
            const float w01 = wx0 * wy1 * ((vx0 && vy1) ? scale : 0.f);
            const float w11 = wx1 * wy1 * ((vx1 && vy1) ? scale : 0.f);

            wA0[k] = (s == 0) ? w00 : ((s == -1) ? w10 : 0.f);
            wB0[k] = (s == 0) ? w10 : ((s == 1) ? w00 : 0.f);
            wA1[k] = (s == 0) ? w01 : ((s == -1) ? w11 : 0.f);
            wB1[k] = (s == 0) ? w11 : ((s == 1) ? w01 : 0.f);

            bx_[k] = bx;
            y0_[k] = y0;
        }

        // staged rows cover clamp(y-1+j), j=0..2. Fast iff every lane's floor
        // row is y-1 or y (then row0=clamp(y0) and row1=clamp(y0+1) are both
        // staged, including image-edge clamping). Verdict is identical across
        // all 4 waves (same pixels) -> block-uniform, barriers safe.
        bool okrow = true;
#pragma unroll
        for (int k = 0; k < CN; ++k)
            okrow = okrow && (y0_[k] >= y - 1) && (y0_[k] <= y);

        if (__all(okrow)) {
            int o0[CN];
#pragma unroll
            for (int k = 0; k < CN; ++k)
                o0[k] = (y0_[k] - y + 1) * 320 + bx_[k];   // staged row j * 320 + col

#pragma unroll 1
            for (int cc = 0; cc < CG; cc += 2) {
                __syncthreads();   // previous phase's reads done before overwrite
                {
                    // stage 2 ch x 3 rows x 320 = 1920 floats = 480 f32x4,
                    // 64 lanes of this group's wave, coalesced 16B/lane.
                    const float* s0 = srcg + (size_t)cc * HW;
#pragma unroll
                    for (int it = 0; it < 8; ++it) {
                        const int idx = it * 64 + p;
                        if (idx < 480) {
                            const int f   = idx << 2;
                            const int chl = (f >= 960) ? 1 : 0;
                            const int rem = f - chl * 960;
                            const int j   = rem / 320;
                            const int col = rem - j * 320;
                            const int row = min(max(y - 1 + j, 0), H - 1);
                            const f32x4 v = *(const f32x4*)(s0 + (size_t)chl * HW + row * W + col);
                            *(f32x4*)&stage[g][f] = v;
                        }
                    }
                }
                __syncthreads();   // staging visible
#pragma unroll
                for (int c2 = 0; c2 < 2; ++c2) {
                    const float rfc = rf[cc + c2];
                    const float* L = &stage[g][c2 * 960];
#pragma unroll
                    for (int k = 0; k < CN; ++k) {
                        const float a0 = L[o0[k]];
                        const float a1 = L[o0[k] + 1];
                        const float b0 = L[o0[k] + 320];
                        const float b1 = L[o0[k] + 321];
                        float t = wA0[k] * a0;
                        t = fmaf(wB0[k], a1, t);
                        t = fmaf(wA1[k], b0, t);
                        t = fmaf(wB1[k], b1, t);
                        volsum[k] = fmaf(rfc, t, volsum[k]);
                    }
                }
            }
        } else {
            // GENERIC fallback (cold on this data): compact global gather.
            int ib0[CN], ib1[CN];
#pragma unroll
            for (int k = 0; k < CN; ++k) {
                const int cy0 = min(max(y0_[k],     0), H - 1);
                const int cy1 = min(max(y0_[k] + 1, 0), H - 1);
                ib0[k] = cy0 * W + bx_[k];
                ib1[k] = cy1 * W + bx_[k];
            }
#pragma unroll 1
            for (int c = 0; c < CG; ++c) {
                const float* fc  = srcg + (size_t)c * HW;
                const float  rfc = rf[c];
#pragma unroll 1
                for (int k = 0; k < CN; ++k) {
                    const f32x2 a   = ld2(fc + ib0[k]);
                    const f32x2 bb2 = ld2(fc + ib1[k]);
                    float t = wA0[k] * a.x;
                    t = fmaf(wB0[k], a.y, t);
                    t = fmaf(wA1[k], bb2.x, t);
                    t = fmaf(wB1[k], bb2.y, t);
                    volsum[k] = fmaf(rfc, t, volsum[k]);
                }
            }
        }
    }

    // cross-group reduce + normalize; sred/sim alias the (now dead) stage buf
    __syncthreads();
#pragma unroll
    for (int k = 0; k < CN; ++k) sredp[(g * CN + k) * 64 + p] = volsum[k];
    __syncthreads();

    {
        const int k = g;   // NG == CN: group g owns depth k = g
        const float s = sredp[(0 * CN + k) * 64 + p] + sredp[(1 * CN + k) * 64 + p]
                      + sredp[(2 * CN + k) * 64 + p] + sredp[(3 * CN + k) * 64 + p];
        simp[k * 64 + p] = s * (1.f / wsum);   // every thread has wsum for its px
    }
    __syncthreads();

    // broadcast-write 128 planes x 64 px (32 KB) with regular cached stores.
    {
        const int quad = tid & 15;
        const int pc   = tid >> 4;
        float* op = out + (size_t)b * C * CN * HW + y * W + xt * 64 + quad * 4;
#pragma unroll
        for (int j = 0; j < 8; ++j) {
            const int plane = pc * 8 + j;          // 0..127, each exactly once
            const int k     = plane & 3;           // == j & 3
            const f32x4 v   = *(const f32x4*)&simp[k * 64 + quad * 4];
            *(f32x4*)(op + (size_t)plane * HW) = v;
        }
    }
}

extern "C" void kernel_launch(void* const* d_in, const int* in_sizes, int n_in,
                              void* d_out, int out_size, void* d_ws, size_t ws_size,
                              hipStream_t stream) {
    const float* depth_values   = (const float*)d_in[0];
    const float* features       = (const float*)d_in[1];
    const float* proj_matrices  = (const float*)d_in[2];
    const float* depth_interval = (const float*)d_in[3];
    const float* view_weights   = (const float*)d_in[7];
    float* out    = (float*)d_out;
    float* params = (float*)d_ws + PARAMS_OFF;    // 96 floats

    setup_proj_kernel<<<1, B, 0, stream>>>(proj_matrices, params);

    fused_kernel<<<NBLK, 256, 0, stream>>>(depth_values, features, depth_interval,
                                           view_weights, params, out);
}